// Round 11
// baseline (389.109 us; speedup 1.0000x reference)
//
#include <hip/hip_runtime.h>
#include <hip/hip_bf16.h>

// BaseQVLayer, R11:
//   xp = x@Wx+bx; yp = y@Wy+by    (k_proj, f32 A staged+converted in-kernel)
//   zT = Wg^T @ xp^T [512 x 8192] (k_zT; associativity: out = A^T@(xp@Wg)+bg)
//   At[j,i] = 2*(yp_j.xp_i)/(Dx_i+Dy_j)   (k_aff, 128x256 tile, wave 64x128)
//   p0/p1 = At @ z split-K halves (k_agg, 1024 blocks, R10-proven)
//   out = relu(p0+p1+bg)                  (k_fin)
//
// R11 deltas vs R10: (1) k_aff geometry 128x256 / wave 64x128 -> 29 FLOP per
// LDS byte (was 16.4) — k_aff is LDS-throughput-bound, not conflict-bound
// (8.4e6 "conflicts" = m134's b128 baseline 4 cyc/read); (2) rcp epilogue;
// (3) k_cvt deleted (k_proj stages f32 directly, R2-proven path).
// LDS-bounce epilogue remains BANNED (R6/R7/R9 failure correlation).
//
// Workspace 138.6 MB: At 128 | xpb 8 | ypb 8 | zT 8 | WxT 1 | WyT 1 | WgT .5
// | Dx,Dy.  p0/p1 alias xpb/ypb (dead after k_aff).

typedef __attribute__((ext_vector_type(8))) short bf16x8;
typedef __attribute__((ext_vector_type(4))) short bf16x4;
typedef __attribute__((ext_vector_type(4))) float f32x4;

__device__ __forceinline__ short f2b(float f) {
    unsigned int u = __builtin_bit_cast(unsigned int, f);
    unsigned int r = (u + 0x7fffu + ((u >> 16) & 1u)) >> 16;
    return (short)r;
}
__device__ __forceinline__ float b2f(short s) {
    unsigned int u = ((unsigned int)(unsigned short)s) << 16;
    return __builtin_bit_cast(float, u);
}

// async global->LDS, 16 B/lane. LDS dest = wave-uniform base + lane*16.
__device__ __forceinline__ void cp16(const void* g, void* l) {
    __builtin_amdgcn_global_load_lds(
        (const __attribute__((address_space(1))) void*)g,
        (__attribute__((address_space(3))) void*)l, 16, 0, 0);
}

constexpr int EPI_XP = 0;  // +bias, store bf16, atomic row-norm
constexpr int EPI_BF = 1;  // store bf16 (zT, k_agg partials)
constexpr int EPI_AT = 2;  // dice scale (rcp), store bf16

constexpr int ASRC_BF16 = 0;
constexpr int ASRC_F32  = 1;  // f32 A, converted during staging (R2-proven)

// C = A @ Bt^T. TM x TN tile, 256 threads (4 waves), BK=32.
// TN=256: waves 2x2, wave 64x128. TN=128: waves 2x2, wave (TM/2)x64.
// TN=64: waves 4x1, wave 32x64.
template<int EPI, int ASRC, int TM, int TN>
__device__ __forceinline__ void gemm_core(
    const void* __restrict__ Aptr, int lda,
    const short* __restrict__ Bt, int ldb,
    int N, int K, int bm, int bn, int kbase,
    const float* __restrict__ bias,
    short* __restrict__ outb,
    float* __restrict__ Dacc,
    const float* __restrict__ Drow, const float* __restrict__ Dcol)
{
    constexpr int WN  = (TN >= 128) ? 2 : 1;       // waves along n
    constexpr int WM  = 4 / WN;                    // waves along m
    constexpr int FRN = TN / WN / 16;              // n-frags per wave
    constexpr int FRM = TM / WM / 16;              // m-frags per wave
    __shared__ __align__(16) short As[TM * 32];
    __shared__ __align__(16) short Bs[TN * 32];

    const int tid  = threadIdx.x;
    const int wave = tid >> 6;
    const int lane = tid & 63;
    const int quad = lane >> 4;
    const int l15  = lane & 15;
    const int wn   = (wave % WN) * (FRN * 16);
    const int wm   = (wave / WN) * (FRM * 16);

    f32x4 acc[FRM][FRN];
#pragma unroll
    for (int i = 0; i < FRM; i++)
#pragma unroll
        for (int j = 0; j < FRN; j++) acc[i][j] = f32x4{0.f, 0.f, 0.f, 0.f};

    for (int k0 = kbase; k0 < kbase + K; k0 += 32) {
        if (ASRC == ASRC_F32) {
            const float* Af = (const float*)Aptr;
#pragma unroll
            for (int s = 0; s < TM * 8 / 256; s++) {   // TM rows x 8 float4
                const int seg = tid + 256 * s;
                const int row = seg >> 3, c4 = seg & 7;
                const float4 v = *(const float4*)&Af[(size_t)(bm + row) * lda + k0 + c4 * 4];
                bf16x4 b;
                b[0] = f2b(v.x); b[1] = f2b(v.y); b[2] = f2b(v.z); b[3] = f2b(v.w);
                *(bf16x4*)&As[row * 32 + c4 * 4] = b;
            }
        } else {
            const short* Ab = (const short*)Aptr;
#pragma unroll
            for (int s = 0; s < TM / 64; s++) {        // TM rows x 4 granules
                const int seg = tid + 256 * s;
                const int row = seg >> 2, c8 = seg & 3;
                cp16(&Ab[(size_t)(bm + row) * lda + k0 + c8 * 8], &As[seg * 8]);
            }
        }
#pragma unroll
        for (int s = 0; s < TN / 64; s++) {            // TN rows x 4 granules
            const int seg = tid + 256 * s;
            const int row = seg >> 2, c8 = seg & 3;
            cp16(&Bt[(size_t)(bn + row) * ldb + k0 + c8 * 8], &Bs[seg * 8]);
        }
        __syncthreads();

        bf16x8 a[FRM], b[FRN];
#pragma unroll
        for (int i = 0; i < FRM; i++)
            a[i] = *(const bf16x8*)&As[(wm + i * 16 + l15) * 32 + quad * 8];
#pragma unroll
        for (int j = 0; j < FRN; j++)
            b[j] = *(const bf16x8*)&Bs[(wn + j * 16 + l15) * 32 + quad * 8];
#pragma unroll
        for (int i = 0; i < FRM; i++)
#pragma unroll
            for (int j = 0; j < FRN; j++)
                acc[i][j] = __builtin_amdgcn_mfma_f32_16x16x32_bf16(a[i], b[j], acc[i][j], 0, 0, 0);
        __syncthreads();
    }

    // C/D layout: col = lane&15, row = quad*4 + r  [m89/m91]
#pragma unroll
    for (int im = 0; im < FRM; ++im) {
#pragma unroll
        for (int r = 0; r < 4; ++r) {
            const int gm = bm + wm + im * 16 + quad * 4 + r;
            if (EPI == EPI_XP) {
                float s = 0.f;
#pragma unroll
                for (int jn = 0; jn < FRN; ++jn) {
                    const int gn = bn + wn + jn * 16 + l15;
                    const float v = acc[im][jn][r] + bias[gn];
                    outb[(size_t)gm * N + gn] = f2b(v);
                    s += v * v;
                }
#pragma unroll
                for (int m = 1; m < 16; m <<= 1) s += __shfl_xor(s, m, 64);
                if (l15 == 0) atomicAdd(&Dacc[gm], s);
            } else if (EPI == EPI_BF) {
#pragma unroll
                for (int jn = 0; jn < FRN; ++jn) {
                    const int gn = bn + wn + jn * 16 + l15;
                    outb[(size_t)gm * N + gn] = f2b(acc[im][jn][r]);
                }
            } else {  // EPI_AT: bf16 out needs 8 mantissa bits -> raw v_rcp ok
                const float dy = Drow[gm];
#pragma unroll
                for (int jn = 0; jn < FRN; ++jn) {
                    const int gn = bn + wn + jn * 16 + l15;
                    const float v = 2.f * acc[im][jn][r] * __builtin_amdgcn_rcpf(Dcol[gn] + dy);
                    outb[(size_t)gm * N + gn] = f2b(v);
                }
            }
        }
    }
}

// xp/yp = x@W + b (f32 A), row norms. grid(4,128), tile 64x128, K=1024.
__global__ __launch_bounds__(256)
void k_proj(const float* __restrict__ A, const short* __restrict__ Bt,
            const float* __restrict__ bias, short* __restrict__ outb,
            float* __restrict__ Dacc)
{
    gemm_core<EPI_XP, ASRC_F32, 64, 128>(A, 1024, Bt, 1024, 512, 1024,
                                         blockIdx.y * 64, blockIdx.x * 128, 0,
                                         bias, outb, Dacc, nullptr, nullptr);
}

// zT = Wg^T @ xp^T  [512 x 8192] bf16. grid(64,8), tile 64x128, K=512.
__global__ __launch_bounds__(256)
void k_zT(const short* __restrict__ WgT, const short* __restrict__ xpb,
          short* __restrict__ zT)
{
    gemm_core<EPI_BF, ASRC_BF16, 64, 128>(WgT, 512, xpb, 512, 8192, 512,
                                          blockIdx.y * 64, blockIdx.x * 128, 0,
                                          nullptr, zT, nullptr, nullptr, nullptr);
}

// At[j,i]. flat grid 2048; tile 128x256, wave 64x128 (29 FLOP/LDS-byte).
// Supertile: 8x8 supertiles of 4bx x 8by blocks; one supertile per XCD pass
// (xp 1 MB + yp 1 MB working set fits 4 MB L2).
__global__ __launch_bounds__(256, 2)
void k_aff(const short* __restrict__ ypb, const short* __restrict__ xpb,
           short* __restrict__ At, const float* __restrict__ Dy,
           const float* __restrict__ Dx)
{
    const int flat = blockIdx.x;
    const int xcd = flat & 7;
    const int q   = flat >> 3;          // 0..255
    const int st  = q >> 5;             // 0..7
    const int w   = q & 31;
    const int s   = xcd * 8 + st;       // global supertile 0..63 (8x8)
    const int bx  = (s & 7) * 4 + (w & 3);    // 0..31  (N/256)
    const int by  = (s >> 3) * 8 + (w >> 2);  // 0..63  (M/128)
    gemm_core<EPI_AT, ASRC_BF16, 128, 256>(ypb, 512, xpb, 512, 8192, 512,
                                           by * 128, bx * 256, 0,
                                           nullptr, At, nullptr, Dy, Dx);
}

// Split-K At@z partials. flat grid 1024 (4 blocks/CU). Group = (bm, z): its
// 8 bn-blocks land on one XCD so the 1 MB At slice is L2-shared. (R10-proven)
__global__ __launch_bounds__(256)
void k_agg(const short* __restrict__ At, const short* __restrict__ zT,
           short* __restrict__ p0, short* __restrict__ p1)
{
    const int flat = blockIdx.x;
    const int xcd = flat & 7;
    const int q   = flat >> 3;            // 0..127 within XCD
    const int g   = xcd * 16 + (q >> 3);  // group 0..127
    const int bm  = (g >> 1) * 128;
    const int z   = g & 1;
    const int bn  = (q & 7) * 64;
    short* outb = z ? p1 : p0;
    gemm_core<EPI_BF, ASRC_BF16, 128, 64>(At, 8192, zT, 8192, 512, 4096,
                                          bm, bn, z * 4096,
                                          nullptr, outb, nullptr, nullptr, nullptr);
}

// out = relu(p0 + p1 + bg). 8 elems/thread, 2048 blocks.
__global__ __launch_bounds__(256)
void k_fin(const short* __restrict__ p0, const short* __restrict__ p1,
           const float* __restrict__ bg, float* __restrict__ out)
{
    const int idx = (blockIdx.x * 256 + threadIdx.x) * 8;
    const int col = idx & 511;
    const bf16x8 a = *(const bf16x8*)&p0[idx];
    const bf16x8 b = *(const bf16x8*)&p1[idx];
    const f32x4 g0 = *(const f32x4*)&bg[col];
    const f32x4 g1 = *(const f32x4*)&bg[col + 4];
    f32x4 o0, o1;
#pragma unroll
    for (int e = 0; e < 4; ++e) {
        o0[e] = fmaxf(b2f(a[e]) + b2f(b[e]) + g0[e], 0.f);
        o1[e] = fmaxf(b2f(a[e + 4]) + b2f(b[e + 4]) + g1[e], 0.f);
    }
    *(f32x4*)&out[idx]     = o0;
    *(f32x4*)&out[idx + 4] = o1;
}

// =========================== helpers =======================================
__global__ __launch_bounds__(256)
void transpose_f32_bf16(const float* __restrict__ in, short* __restrict__ out, int R, int C)
{
    __shared__ short t[32][33];
    const int tx = threadIdx.x, ty = threadIdx.y;
    const int bx = blockIdx.x * 32, by = blockIdx.y * 32;
#pragma unroll
    for (int i = 0; i < 32; i += 8)
        t[ty + i][tx] = f2b(in[(size_t)(by + ty + i) * C + bx + tx]);
    __syncthreads();
#pragma unroll
    for (int i = 0; i < 32; i += 8)
        out[(size_t)(bx + ty + i) * R + by + tx] = t[tx][ty + i];
}

extern "C" void kernel_launch(void* const* d_in, const int* in_sizes, int n_in,
                              void* d_out, int out_size, void* d_ws, size_t ws_size,
                              hipStream_t stream)
{
    const float* x  = (const float*)d_in[0];
    const float* y  = (const float*)d_in[1];
    const float* Wx = (const float*)d_in[2];
    const float* bx = (const float*)d_in[3];
    const float* Wy = (const float*)d_in[4];
    const float* by = (const float*)d_in[5];
    const float* Wg = (const float*)d_in[6];
    const float* bg = (const float*)d_in[7];
    float* out = (float*)d_out;                // [8192, 512] f32

    char* p = (char*)d_ws;
    short* At   = (short*)p; p += (size_t)8192 * 8192 * 2;
    short* xpb  = (short*)p; p += (size_t)8192 * 512 * 2;
    short* ypb  = (short*)p; p += (size_t)8192 * 512 * 2;
    short* zT   = (short*)p; p += (size_t)512 * 8192 * 2;
    short* WxT  = (short*)p; p += (size_t)512 * 1024 * 2;
    short* WyT  = (short*)p; p += (size_t)512 * 1024 * 2;
    short* WgT  = (short*)p; p += (size_t)512 * 512 * 2;
    float* Dx   = (float*)p; p += (size_t)8192 * 4;
    float* Dy   = (float*)p; p += (size_t)8192 * 4;
    // split-K partials alias xpb/ypb (dead after k_aff)
    short* p0 = xpb;
    short* p1 = ypb;

    hipMemsetAsync(Dx, 0, 2 * 8192 * sizeof(float), stream);  // Dx,Dy contiguous

    dim3 tb(32, 8);
    transpose_f32_bf16<<<dim3(512 / 32, 1024 / 32), tb, 0, stream>>>(Wx, WxT, 1024, 512);
    transpose_f32_bf16<<<dim3(512 / 32, 1024 / 32), tb, 0, stream>>>(Wy, WyT, 1024, 512);
    transpose_f32_bf16<<<dim3(512 / 32, 512 / 32),  tb, 0, stream>>>(Wg, WgT, 512, 512);

    k_proj<<<dim3(4, 128), 256, 0, stream>>>(x, WxT, bx, xpb, Dx);
    k_proj<<<dim3(4, 128), 256, 0, stream>>>(y, WyT, by, ypb, Dy);

    k_zT<<<dim3(64, 8), 256, 0, stream>>>(WgT, xpb, zT);

    k_aff<<<2048, 256, 0, stream>>>(ypb, xpb, At, Dy, Dx);

    k_agg<<<1024, 256, 0, stream>>>(At, zT, p0, p1);

    k_fin<<<2048, 256, 0, stream>>>(p0, p1, bg, out);
}

// Round 12
// 372.250 us; speedup vs baseline: 1.0453x; 1.0453x over previous
//
#include <hip/hip_runtime.h>
#include <hip/hip_bf16.h>

// BaseQVLayer, R12:
//   xb/yb = bf16(x/y)             (k_cvt — restored; f32-staging k_proj was
//                                  +37us vs cp16-bf16, R11 post-mortem)
//   xp = x@Wx+bx; yp = y@Wy+by    (k_proj + row-norms, cp16 bf16 A)
//   zT = Wg^T @ xp^T [512 x 8192] (k_zT; out = A^T@(xp@Wg)+bg associativity)
//   At[j,i] = 2*(yp_j.xp_i)/(Dx_i+Dy_j)   (k_aff, 128x256, wave 64x128)
//   p0/p1 = At @ z split-K halves (k_agg, 1024 blocks = 4/CU)
//   out = relu(p0+p1+bg)                  (k_fin)
//
// R12 delta: 2-bit XOR granule swizzle (slot = g ^ (row&3)) on LDS staging +
// frag reads — device-proven by R5's k_fuse. Fixes the 8-way bank alias of
// the unpadded stride-32 layout (1.26e7 conflict cycles = ~19% of k_agg CU
// time) down to 4-way (1.58x, m136). cp16 forbids padding (wave-uniform dest).
// LDS-bounce epilogue remains BANNED (R6/R7/R9). BK=64 still quarantined.
//
// Workspace 154.6 MB: At [0,128 MB) with xb@0 / yb@16MB aliased (dead before
// k_aff); xpb 8 | ypb 8 | zT 8 | WxT 1 | WyT 1 | WgT .5 | Dx,Dy.
// p0/p1 alias xpb/ypb (dead after k_aff).

typedef __attribute__((ext_vector_type(8))) short bf16x8;
typedef __attribute__((ext_vector_type(4))) short bf16x4;
typedef __attribute__((ext_vector_type(4))) float f32x4;

__device__ __forceinline__ short f2b(float f) {
    unsigned int u = __builtin_bit_cast(unsigned int, f);
    unsigned int r = (u + 0x7fffu + ((u >> 16) & 1u)) >> 16;
    return (short)r;
}
__device__ __forceinline__ float b2f(short s) {
    unsigned int u = ((unsigned int)(unsigned short)s) << 16;
    return __builtin_bit_cast(float, u);
}

// async global->LDS, 16 B/lane. LDS dest = wave-uniform base + lane*16.
__device__ __forceinline__ void cp16(const void* g, void* l) {
    __builtin_amdgcn_global_load_lds(
        (const __attribute__((address_space(1))) void*)g,
        (__attribute__((address_space(3))) void*)l, 16, 0, 0);
}

constexpr int EPI_XP = 0;  // +bias, store bf16, atomic row-norm
constexpr int EPI_BF = 1;  // store bf16 (zT, k_agg partials)
constexpr int EPI_AT = 2;  // dice scale (rcp), store bf16

// C = A @ Bt^T. TM x TN tile, 256 threads (4 waves), BK=32, bf16 cp16 staging.
// LDS granule slot = g ^ (row&3)  [2-bit XOR swizzle, R5-proven].
// TN=256: waves 2x2, wave 64x128. TN=128: waves 2x2, wave (TM/2)x64.
// TN=64: waves 4x1, wave 32x64.
template<int EPI, int TM, int TN>
__device__ __forceinline__ void gemm_core(
    const short* __restrict__ A, int lda,
    const short* __restrict__ Bt, int ldb,
    int N, int K, int bm, int bn, int kbase,
    const float* __restrict__ bias,
    short* __restrict__ outb,
    float* __restrict__ Dacc,
    const float* __restrict__ Drow, const float* __restrict__ Dcol)
{
    constexpr int WN  = (TN >= 128) ? 2 : 1;       // waves along n
    constexpr int WM  = 4 / WN;                    // waves along m
    constexpr int FRN = TN / WN / 16;              // n-frags per wave
    constexpr int FRM = TM / WM / 16;              // m-frags per wave
    __shared__ __align__(16) short As[TM * 32];
    __shared__ __align__(16) short Bs[TN * 32];

    const int tid  = threadIdx.x;
    const int wave = tid >> 6;
    const int lane = tid & 63;
    const int quad = lane >> 4;
    const int l15  = lane & 15;
    const int wn   = (wave % WN) * (FRN * 16);
    const int wm   = (wave / WN) * (FRM * 16);

    f32x4 acc[FRM][FRN];
#pragma unroll
    for (int i = 0; i < FRM; i++)
#pragma unroll
        for (int j = 0; j < FRN; j++) acc[i][j] = f32x4{0.f, 0.f, 0.f, 0.f};

    for (int k0 = kbase; k0 < kbase + K; k0 += 32) {
#pragma unroll
        for (int s = 0; s < TM / 64; s++) {        // A: TM rows x 4 granules
            const int seg = tid + 256 * s;
            const int row = seg >> 2, c8 = seg & 3;
            const int gg  = c8 ^ (row & 3);        // slot c8 holds granule gg
            cp16(&A[(size_t)(bm + row) * lda + k0 + gg * 8], &As[seg * 8]);
        }
#pragma unroll
        for (int s = 0; s < TN / 64; s++) {        // B: TN rows x 4 granules
            const int seg = tid + 256 * s;
            const int row = seg >> 2, c8 = seg & 3;
            const int gg  = c8 ^ (row & 3);
            cp16(&Bt[(size_t)(bn + row) * ldb + k0 + gg * 8], &Bs[seg * 8]);
        }
        __syncthreads();

        bf16x8 a[FRM], b[FRN];
#pragma unroll
        for (int i = 0; i < FRM; i++) {
            const int row = wm + i * 16 + l15;
            a[i] = *(const bf16x8*)&As[row * 32 + ((quad ^ (row & 3)) << 3)];
        }
#pragma unroll
        for (int j = 0; j < FRN; j++) {
            const int row = wn + j * 16 + l15;
            b[j] = *(const bf16x8*)&Bs[row * 32 + ((quad ^ (row & 3)) << 3)];
        }
#pragma unroll
        for (int i = 0; i < FRM; i++)
#pragma unroll
            for (int j = 0; j < FRN; j++)
                acc[i][j] = __builtin_amdgcn_mfma_f32_16x16x32_bf16(a[i], b[j], acc[i][j], 0, 0, 0);
        __syncthreads();
    }

    // C/D layout: col = lane&15, row = quad*4 + r  [m89/m91]
#pragma unroll
    for (int im = 0; im < FRM; ++im) {
#pragma unroll
        for (int r = 0; r < 4; ++r) {
            const int gm = bm + wm + im * 16 + quad * 4 + r;
            if (EPI == EPI_XP) {
                float s = 0.f;
#pragma unroll
                for (int jn = 0; jn < FRN; ++jn) {
                    const int gn = bn + wn + jn * 16 + l15;
                    const float v = acc[im][jn][r] + bias[gn];
                    outb[(size_t)gm * N + gn] = f2b(v);
                    s += v * v;
                }
#pragma unroll
                for (int m = 1; m < 16; m <<= 1) s += __shfl_xor(s, m, 64);
                if (l15 == 0) atomicAdd(&Dacc[gm], s);
            } else if (EPI == EPI_BF) {
#pragma unroll
                for (int jn = 0; jn < FRN; ++jn) {
                    const int gn = bn + wn + jn * 16 + l15;
                    outb[(size_t)gm * N + gn] = f2b(acc[im][jn][r]);
                }
            } else {  // EPI_AT: bf16 out needs 8 mantissa bits -> raw v_rcp ok
                const float dy = Drow[gm];
#pragma unroll
                for (int jn = 0; jn < FRN; ++jn) {
                    const int gn = bn + wn + jn * 16 + l15;
                    const float v = 2.f * acc[im][jn][r] * __builtin_amdgcn_rcpf(Dcol[gn] + dy);
                    outb[(size_t)gm * N + gn] = f2b(v);
                }
            }
        }
    }
}

// xp/yp = x@W + b (bf16 A via cp16), row norms. grid(4,128), tile 64x128.
__global__ __launch_bounds__(256)
void k_proj(const short* __restrict__ A, const short* __restrict__ Bt,
            const float* __restrict__ bias, short* __restrict__ outb,
            float* __restrict__ Dacc)
{
    gemm_core<EPI_XP, 64, 128>(A, 1024, Bt, 1024, 512, 1024,
                               blockIdx.y * 64, blockIdx.x * 128, 0,
                               bias, outb, Dacc, nullptr, nullptr);
}

// zT = Wg^T @ xp^T  [512 x 8192] bf16. grid(64,8), tile 64x128, K=512.
__global__ __launch_bounds__(256)
void k_zT(const short* __restrict__ WgT, const short* __restrict__ xpb,
          short* __restrict__ zT)
{
    gemm_core<EPI_BF, 64, 128>(WgT, 512, xpb, 512, 8192, 512,
                               blockIdx.y * 64, blockIdx.x * 128, 0,
                               nullptr, zT, nullptr, nullptr, nullptr);
}

// At[j,i]. flat grid 2048; tile 128x256, wave 64x128 (R11-proven geometry).
// Supertile: 8x8 supertiles of 4bx x 8by blocks; one supertile per XCD
// (xp 1 MB + yp 1 MB working set fits 4 MB L2).
__global__ __launch_bounds__(256, 2)
void k_aff(const short* __restrict__ ypb, const short* __restrict__ xpb,
           short* __restrict__ At, const float* __restrict__ Dy,
           const float* __restrict__ Dx)
{
    const int flat = blockIdx.x;
    const int xcd = flat & 7;
    const int q   = flat >> 3;          // 0..255
    const int st  = q >> 5;             // 0..7
    const int w   = q & 31;
    const int s   = xcd * 8 + st;       // global supertile 0..63 (8x8)
    const int bx  = (s & 7) * 4 + (w & 3);    // 0..31  (N/256)
    const int by  = (s >> 3) * 8 + (w >> 2);  // 0..63  (M/128)
    gemm_core<EPI_AT, 128, 256>(ypb, 512, xpb, 512, 8192, 512,
                                by * 128, bx * 256, 0,
                                nullptr, At, nullptr, Dy, Dx);
}

// Split-K At@z partials. flat grid 1024 (4 blocks/CU). Group = (bm, z): its
// 8 bn-blocks land on one XCD so the 1 MB At slice is L2-shared. (R10-proven)
__global__ __launch_bounds__(256)
void k_agg(const short* __restrict__ At, const short* __restrict__ zT,
           short* __restrict__ p0, short* __restrict__ p1)
{
    const int flat = blockIdx.x;
    const int xcd = flat & 7;
    const int q   = flat >> 3;            // 0..127 within XCD
    const int g   = xcd * 16 + (q >> 3);  // group 0..127
    const int bm  = (g >> 1) * 128;
    const int z   = g & 1;
    const int bn  = (q & 7) * 64;
    short* outb = z ? p1 : p0;
    gemm_core<EPI_BF, 128, 64>(At, 8192, zT, 8192, 512, 4096,
                               bm, bn, z * 4096,
                               nullptr, outb, nullptr, nullptr, nullptr);
}

// out = relu(p0 + p1 + bg). 8 elems/thread, 2048 blocks.
__global__ __launch_bounds__(256)
void k_fin(const short* __restrict__ p0, const short* __restrict__ p1,
           const float* __restrict__ bg, float* __restrict__ out)
{
    const int idx = (blockIdx.x * 256 + threadIdx.x) * 8;
    const int col = idx & 511;
    const bf16x8 a = *(const bf16x8*)&p0[idx];
    const bf16x8 b = *(const bf16x8*)&p1[idx];
    const f32x4 g0 = *(const f32x4*)&bg[col];
    const f32x4 g1 = *(const f32x4*)&bg[col + 4];
    f32x4 o0, o1;
#pragma unroll
    for (int e = 0; e < 4; ++e) {
        o0[e] = fmaxf(b2f(a[e]) + b2f(b[e]) + g0[e], 0.f);
        o1[e] = fmaxf(b2f(a[e + 4]) + b2f(b[e + 4]) + g1[e], 0.f);
    }
    *(f32x4*)&out[idx]     = o0;
    *(f32x4*)&out[idx + 4] = o1;
}

// =========================== helpers =======================================
__global__ __launch_bounds__(256)
void k_cvt(const float* __restrict__ in, short* __restrict__ out)
{
    const int i = (blockIdx.x * 256 + threadIdx.x) * 4;
    const float4 v = *(const float4*)&in[i];
    bf16x4 b;
    b[0] = f2b(v.x); b[1] = f2b(v.y); b[2] = f2b(v.z); b[3] = f2b(v.w);
    *(bf16x4*)&out[i] = b;
}

__global__ __launch_bounds__(256)
void transpose_f32_bf16(const float* __restrict__ in, short* __restrict__ out, int R, int C)
{
    __shared__ short t[32][33];
    const int tx = threadIdx.x, ty = threadIdx.y;
    const int bx = blockIdx.x * 32, by = blockIdx.y * 32;
#pragma unroll
    for (int i = 0; i < 32; i += 8)
        t[ty + i][tx] = f2b(in[(size_t)(by + ty + i) * C + bx + tx]);
    __syncthreads();
#pragma unroll
    for (int i = 0; i < 32; i += 8)
        out[(size_t)(bx + ty + i) * R + by + tx] = t[tx][ty + i];
}

extern "C" void kernel_launch(void* const* d_in, const int* in_sizes, int n_in,
                              void* d_out, int out_size, void* d_ws, size_t ws_size,
                              hipStream_t stream)
{
    const float* x  = (const float*)d_in[0];
    const float* y  = (const float*)d_in[1];
    const float* Wx = (const float*)d_in[2];
    const float* bx = (const float*)d_in[3];
    const float* Wy = (const float*)d_in[4];
    const float* by = (const float*)d_in[5];
    const float* Wg = (const float*)d_in[6];
    const float* bg = (const float*)d_in[7];
    float* out = (float*)d_out;                // [8192, 512] f32

    char* p = (char*)d_ws;
    short* At   = (short*)p;                   // [0, 128 MB)
    short* xb   = (short*)p;                   // 16 MB, aliases At (dead by k_aff)
    short* yb   = (short*)(p + (size_t)8192 * 1024 * 2);   // next 16 MB, ditto
    p += (size_t)8192 * 8192 * 2;
    short* xpb  = (short*)p; p += (size_t)8192 * 512 * 2;
    short* ypb  = (short*)p; p += (size_t)8192 * 512 * 2;
    short* zT   = (short*)p; p += (size_t)512 * 8192 * 2;
    short* WxT  = (short*)p; p += (size_t)512 * 1024 * 2;
    short* WyT  = (short*)p; p += (size_t)512 * 1024 * 2;
    short* WgT  = (short*)p; p += (size_t)512 * 512 * 2;
    float* Dx   = (float*)p; p += (size_t)8192 * 4;
    float* Dy   = (float*)p; p += (size_t)8192 * 4;
    // split-K partials alias xpb/ypb (dead after k_aff)
    short* p0 = xpb;
    short* p1 = ypb;

    hipMemsetAsync(Dx, 0, 2 * 8192 * sizeof(float), stream);  // Dx,Dy contiguous

    dim3 tb(32, 8);
    transpose_f32_bf16<<<dim3(512 / 32, 1024 / 32), tb, 0, stream>>>(Wx, WxT, 1024, 512);
    transpose_f32_bf16<<<dim3(512 / 32, 1024 / 32), tb, 0, stream>>>(Wy, WyT, 1024, 512);
    transpose_f32_bf16<<<dim3(512 / 32, 512 / 32),  tb, 0, stream>>>(Wg, WgT, 512, 512);

    k_cvt<<<8192, 256, 0, stream>>>(x, xb);
    k_cvt<<<8192, 256, 0, stream>>>(y, yb);

    k_proj<<<dim3(4, 128), 256, 0, stream>>>(xb, WxT, bx, xpb, Dx);
    k_proj<<<dim3(4, 128), 256, 0, stream>>>(yb, WyT, by, ypb, Dy);

    k_zT<<<dim3(64, 8), 256, 0, stream>>>(WgT, xpb, zT);

    k_aff<<<2048, 256, 0, stream>>>(ypb, xpb, At, Dy, Dx);

    k_agg<<<1024, 256, 0, stream>>>(At, zT, p0, p1);

    k_fin<<<2048, 256, 0, stream>>>(p0, p1, bg, out);
}

// Round 13
// 355.261 us; speedup vs baseline: 1.0953x; 1.0478x over previous
//
#include <hip/hip_runtime.h>
#include <hip/hip_bf16.h>

// BaseQVLayer, R13:
//   xb/yb = bf16(x/y)             (k_cvt)
//   xp = x@Wx+bx; yp = y@Wy+by    (k_proj + row-norms, cp16 bf16 A)
//   zT = Wg^T @ xp^T [512 x 8192] (k_zT; out = A^T@(xp@Wg)+bg associativity)
//   At[j,i] = 2*(yp_j.xp_i)/(Dx_i+Dy_j)   (k_aff, 128x256, wave 64x128)
//   p0/p1 = At @ z split-K halves (k_agg, tile 128x128, wave 64x64, 512 blk)
//   out = relu(p0+p1+bg)                  (k_fin)
//
// R13 delta: k_agg TN 64->128 (wave 32x64 -> 64x64). k_agg is
// LDS-THROUGHPUT-bound (R12 model: 144 KB LDS/iter/CU = 1700 cyc vs 620 cyc
// MFMA); 64x64 waves cut frag bytes/MFMA 0.75 -> 0.5 KB. Occupancy 4->2
// blocks/CU accepted: LDS-bound kernels queue on the LDS unit, not latency.
// NOTE R12 lesson: SQ_LDS_BANK_CONFLICT ~1.26e7 is the STRUCTURAL wave64
// b128 8-pass minimum — XOR swizzle provably does not move it (kept anyway,
// harmless). LDS-bounce epilogue remains BANNED (R6/R7/R9).
//
// Workspace 154.6 MB: At [0,128 MB) with xb@0 / yb@16MB aliased (dead before
// k_aff); xpb 8 | ypb 8 | zT 8 | WxT 1 | WyT 1 | WgT .5 | Dx,Dy.
// p0/p1 alias xpb/ypb (dead after k_aff).

typedef __attribute__((ext_vector_type(8))) short bf16x8;
typedef __attribute__((ext_vector_type(4))) short bf16x4;
typedef __attribute__((ext_vector_type(4))) float f32x4;

__device__ __forceinline__ short f2b(float f) {
    unsigned int u = __builtin_bit_cast(unsigned int, f);
    unsigned int r = (u + 0x7fffu + ((u >> 16) & 1u)) >> 16;
    return (short)r;
}
__device__ __forceinline__ float b2f(short s) {
    unsigned int u = ((unsigned int)(unsigned short)s) << 16;
    return __builtin_bit_cast(float, u);
}

// async global->LDS, 16 B/lane. LDS dest = wave-uniform base + lane*16.
__device__ __forceinline__ void cp16(const void* g, void* l) {
    __builtin_amdgcn_global_load_lds(
        (const __attribute__((address_space(1))) void*)g,
        (__attribute__((address_space(3))) void*)l, 16, 0, 0);
}

constexpr int EPI_XP = 0;  // +bias, store bf16, atomic row-norm
constexpr int EPI_BF = 1;  // store bf16 (zT, k_agg partials)
constexpr int EPI_AT = 2;  // dice scale (rcp), store bf16

// C = A @ Bt^T. TM x TN tile, 256 threads (4 waves), BK=32, bf16 cp16 staging.
// LDS granule slot = g ^ (row&3). Wave layout via WVN template arg:
// WVN=2: waves 2x2 (wave tile (TM/2) x (TN/2)); WVN=1: waves 4x1.
template<int EPI, int TM, int TN, int WVN>
__device__ __forceinline__ void gemm_core(
    const short* __restrict__ A, int lda,
    const short* __restrict__ Bt, int ldb,
    int N, int K, int bm, int bn, int kbase,
    const float* __restrict__ bias,
    short* __restrict__ outb,
    float* __restrict__ Dacc,
    const float* __restrict__ Drow, const float* __restrict__ Dcol)
{
    constexpr int WN  = WVN;                       // waves along n
    constexpr int WM  = 4 / WN;                    // waves along m
    constexpr int FRN = TN / WN / 16;              // n-frags per wave
    constexpr int FRM = TM / WM / 16;              // m-frags per wave
    __shared__ __align__(16) short As[TM * 32];
    __shared__ __align__(16) short Bs[TN * 32];

    const int tid  = threadIdx.x;
    const int wave = tid >> 6;
    const int lane = tid & 63;
    const int quad = lane >> 4;
    const int l15  = lane & 15;
    const int wn   = (wave % WN) * (FRN * 16);
    const int wm   = (wave / WN) * (FRM * 16);

    f32x4 acc[FRM][FRN];
#pragma unroll
    for (int i = 0; i < FRM; i++)
#pragma unroll
        for (int j = 0; j < FRN; j++) acc[i][j] = f32x4{0.f, 0.f, 0.f, 0.f};

    for (int k0 = kbase; k0 < kbase + K; k0 += 32) {
#pragma unroll
        for (int s = 0; s < TM / 64; s++) {        // A: TM rows x 4 granules
            const int seg = tid + 256 * s;
            const int row = seg >> 2, c8 = seg & 3;
            const int gg  = c8 ^ (row & 3);        // slot c8 holds granule gg
            cp16(&A[(size_t)(bm + row) * lda + k0 + gg * 8], &As[seg * 8]);
        }
#pragma unroll
        for (int s = 0; s < TN / 64; s++) {        // B: TN rows x 4 granules
            const int seg = tid + 256 * s;
            const int row = seg >> 2, c8 = seg & 3;
            const int gg  = c8 ^ (row & 3);
            cp16(&Bt[(size_t)(bn + row) * ldb + k0 + gg * 8], &Bs[seg * 8]);
        }
        __syncthreads();

        bf16x8 a[FRM], b[FRN];
#pragma unroll
        for (int i = 0; i < FRM; i++) {
            const int row = wm + i * 16 + l15;
            a[i] = *(const bf16x8*)&As[row * 32 + ((quad ^ (row & 3)) << 3)];
        }
#pragma unroll
        for (int j = 0; j < FRN; j++) {
            const int row = wn + j * 16 + l15;
            b[j] = *(const bf16x8*)&Bs[row * 32 + ((quad ^ (row & 3)) << 3)];
        }
#pragma unroll
        for (int i = 0; i < FRM; i++)
#pragma unroll
            for (int j = 0; j < FRN; j++)
                acc[i][j] = __builtin_amdgcn_mfma_f32_16x16x32_bf16(a[i], b[j], acc[i][j], 0, 0, 0);
        __syncthreads();
    }

    // C/D layout: col = lane&15, row = quad*4 + r  [m89/m91]
#pragma unroll
    for (int im = 0; im < FRM; ++im) {
#pragma unroll
        for (int r = 0; r < 4; ++r) {
            const int gm = bm + wm + im * 16 + quad * 4 + r;
            if (EPI == EPI_XP) {
                float s = 0.f;
#pragma unroll
                for (int jn = 0; jn < FRN; ++jn) {
                    const int gn = bn + wn + jn * 16 + l15;
                    const float v = acc[im][jn][r] + bias[gn];
                    outb[(size_t)gm * N + gn] = f2b(v);
                    s += v * v;
                }
#pragma unroll
                for (int m = 1; m < 16; m <<= 1) s += __shfl_xor(s, m, 64);
                if (l15 == 0) atomicAdd(&Dacc[gm], s);
            } else if (EPI == EPI_BF) {
#pragma unroll
                for (int jn = 0; jn < FRN; ++jn) {
                    const int gn = bn + wn + jn * 16 + l15;
                    outb[(size_t)gm * N + gn] = f2b(acc[im][jn][r]);
                }
            } else {  // EPI_AT: bf16 out needs 8 mantissa bits -> raw v_rcp ok
                const float dy = Drow[gm];
#pragma unroll
                for (int jn = 0; jn < FRN; ++jn) {
                    const int gn = bn + wn + jn * 16 + l15;
                    const float v = 2.f * acc[im][jn][r] * __builtin_amdgcn_rcpf(Dcol[gn] + dy);
                    outb[(size_t)gm * N + gn] = f2b(v);
                }
            }
        }
    }
}

// xp/yp = x@W + b (bf16 A via cp16), row norms. grid(4,128), tile 64x128.
__global__ __launch_bounds__(256)
void k_proj(const short* __restrict__ A, const short* __restrict__ Bt,
            const float* __restrict__ bias, short* __restrict__ outb,
            float* __restrict__ Dacc)
{
    gemm_core<EPI_XP, 64, 128, 2>(A, 1024, Bt, 1024, 512, 1024,
                                  blockIdx.y * 64, blockIdx.x * 128, 0,
                                  bias, outb, Dacc, nullptr, nullptr);
}

// zT = Wg^T @ xp^T  [512 x 8192] bf16. grid(64,8), tile 64x128, K=512.
__global__ __launch_bounds__(256)
void k_zT(const short* __restrict__ WgT, const short* __restrict__ xpb,
          short* __restrict__ zT)
{
    gemm_core<EPI_BF, 64, 128, 2>(WgT, 512, xpb, 512, 8192, 512,
                                  blockIdx.y * 64, blockIdx.x * 128, 0,
                                  nullptr, zT, nullptr, nullptr, nullptr);
}

// At[j,i]. flat grid 2048; tile 128x256, wave 64x128 (R11-proven geometry).
// Supertile: one 4bx x 8by supertile per XCD (xp+yp 2 MB fits 4 MB L2).
__global__ __launch_bounds__(256, 2)
void k_aff(const short* __restrict__ ypb, const short* __restrict__ xpb,
           short* __restrict__ At, const float* __restrict__ Dy,
           const float* __restrict__ Dx)
{
    const int flat = blockIdx.x;
    const int xcd = flat & 7;
    const int q   = flat >> 3;          // 0..255
    const int st  = q >> 5;             // 0..7
    const int w   = q & 31;
    const int s   = xcd * 8 + st;       // global supertile 0..63 (8x8)
    const int bx  = (s & 7) * 4 + (w & 3);    // 0..31  (N/256)
    const int by  = (s >> 3) * 8 + (w >> 2);  // 0..63  (M/128)
    gemm_core<EPI_AT, 128, 256, 2>(ypb, 512, xpb, 512, 8192, 512,
                                   by * 128, bx * 256, 0,
                                   nullptr, At, nullptr, Dy, Dx);
}

// Split-K At@z partials. tile 128x128, wave 64x64 (0.5 KB LDS/MFMA), flat
// grid 512 (2 blocks/CU). Group = (bm,z): its 4 bn-blocks on one XCD so the
// 1 MB At slice is L2-shared; z-halves read disjoint At columns.
__global__ __launch_bounds__(256)
void k_agg(const short* __restrict__ At, const short* __restrict__ zT,
           short* __restrict__ p0, short* __restrict__ p1)
{
    const int flat = blockIdx.x;
    const int xcd = flat & 7;
    const int q   = flat >> 3;            // 0..63 within XCD
    const int g   = xcd * 16 + (q >> 2);  // group 0..127 = (bm, z)
    const int bm  = (g >> 1) * 128;
    const int z   = g & 1;
    const int bn  = (q & 3) * 128;
    short* outb = z ? p1 : p0;
    gemm_core<EPI_BF, 128, 128, 2>(At, 8192, zT, 8192, 512, 4096,
                                   bm, bn, z * 4096,
                                   nullptr, outb, nullptr, nullptr, nullptr);
}

// out = relu(p0 + p1 + bg). 8 elems/thread, 2048 blocks.
__global__ __launch_bounds__(256)
void k_fin(const short* __restrict__ p0, const short* __restrict__ p1,
           const float* __restrict__ bg, float* __restrict__ out)
{
    const int idx = (blockIdx.x * 256 + threadIdx.x) * 8;
    const int col = idx & 511;
    const bf16x8 a = *(const bf16x8*)&p0[idx];
    const bf16x8 b = *(const bf16x8*)&p1[idx];
    const f32x4 g0 = *(const f32x4*)&bg[col];
    const f32x4 g1 = *(const f32x4*)&bg[col + 4];
    f32x4 o0, o1;
#pragma unroll
    for (int e = 0; e < 4; ++e) {
        o0[e] = fmaxf(b2f(a[e]) + b2f(b[e]) + g0[e], 0.f);
        o1[e] = fmaxf(b2f(a[e + 4]) + b2f(b[e + 4]) + g1[e], 0.f);
    }
    *(f32x4*)&out[idx]     = o0;
    *(f32x4*)&out[idx + 4] = o1;
}

// =========================== helpers =======================================
__global__ __launch_bounds__(256)
void k_cvt(const float* __restrict__ in, short* __restrict__ out)
{
    const int i = (blockIdx.x * 256 + threadIdx.x) * 4;
    const float4 v = *(const float4*)&in[i];
    bf16x4 b;
    b[0] = f2b(v.x); b[1] = f2b(v.y); b[2] = f2b(v.z); b[3] = f2b(v.w);
    *(bf16x4*)&out[i] = b;
}

__global__ __launch_bounds__(256)
void transpose_f32_bf16(const float* __restrict__ in, short* __restrict__ out, int R, int C)
{
    __shared__ short t[32][33];
    const int tx = threadIdx.x, ty = threadIdx.y;
    const int bx = blockIdx.x * 32, by = blockIdx.y * 32;
#pragma unroll
    for (int i = 0; i < 32; i += 8)
        t[ty + i][tx] = f2b(in[(size_t)(by + ty + i) * C + bx + tx]);
    __syncthreads();
#pragma unroll
    for (int i = 0; i < 32; i += 8)
        out[(size_t)(bx + ty + i) * R + by + tx] = t[tx][ty + i];
}

extern "C" void kernel_launch(void* const* d_in, const int* in_sizes, int n_in,
                              void* d_out, int out_size, void* d_ws, size_t ws_size,
                              hipStream_t stream)
{
    const float* x  = (const float*)d_in[0];
    const float* y  = (const float*)d_in[1];
    const float* Wx = (const float*)d_in[2];
    const float* bx = (const float*)d_in[3];
    const float* Wy = (const float*)d_in[4];
    const float* by = (const float*)d_in[5];
    const float* Wg = (const float*)d_in[6];
    const float* bg = (const float*)d_in[7];
    float* out = (float*)d_out;                // [8192, 512] f32

    char* p = (char*)d_ws;
    short* At   = (short*)p;                   // [0, 128 MB)
    short* xb   = (short*)p;                   // 16 MB, aliases At (dead by k_aff)
    short* yb   = (short*)(p + (size_t)8192 * 1024 * 2);   // next 16 MB, ditto
    p += (size_t)8192 * 8192 * 2;
    short* xpb  = (short*)p; p += (size_t)8192 * 512 * 2;
    short* ypb  = (short*)p; p += (size_t)8192 * 512 * 2;
    short* zT   = (short*)p; p += (size_t)512 * 8192 * 2;
    short* WxT  = (short*)p; p += (size_t)512 * 1024 * 2;
    short* WyT  = (short*)p; p += (size_t)512 * 1024 * 2;
    short* WgT  = (short*)p; p += (size_t)512 * 512 * 2;
    float* Dx   = (float*)p; p += (size_t)8192 * 4;
    float* Dy   = (float*)p; p += (size_t)8192 * 4;
    // split-K partials alias xpb/ypb (dead after k_aff)
    short* p0 = xpb;
    short* p1 = ypb;

    hipMemsetAsync(Dx, 0, 2 * 8192 * sizeof(float), stream);  // Dx,Dy contiguous

    dim3 tb(32, 8);
    transpose_f32_bf16<<<dim3(512 / 32, 1024 / 32), tb, 0, stream>>>(Wx, WxT, 1024, 512);
    transpose_f32_bf16<<<dim3(512 / 32, 1024 / 32), tb, 0, stream>>>(Wy, WyT, 1024, 512);
    transpose_f32_bf16<<<dim3(512 / 32, 512 / 32),  tb, 0, stream>>>(Wg, WgT, 512, 512);

    k_cvt<<<8192, 256, 0, stream>>>(x, xb);
    k_cvt<<<8192, 256, 0, stream>>>(y, yb);

    k_proj<<<dim3(4, 128), 256, 0, stream>>>(xb, WxT, bx, xpb, Dx);
    k_proj<<<dim3(4, 128), 256, 0, stream>>>(yb, WyT, by, ypb, Dy);

    k_zT<<<dim3(64, 8), 256, 0, stream>>>(WgT, xpb, zT);

    k_aff<<<2048, 256, 0, stream>>>(ypb, xpb, At, Dy, Dx);

    k_agg<<<512, 256, 0, stream>>>(At, zT, p0, p1);

    k_fin<<<2048, 256, 0, stream>>>(p0, p1, bg, out);
}